// Round 2
// baseline (360.454 us; speedup 1.0000x reference)
//
#include <hip/hip_runtime.h>

#define BB 32
#define LL 512
#define EMB 128
#define RS 11
#define RR 5
#define NR 64                 // output rows per block (64 | 512, so one b per block)
#define NSLOT (NR + RS - 1)   // 74 real position slots: p in [l0-5, l0+68]
#define NSLOTP 80             // padded: 4 waves x 20 slots

typedef float f4 __attribute__((ext_vector_type(4)));

__global__ __launch_bounds__(256) void region_encoder_kernel(
    const int* __restrict__ seq,
    const float* __restrict__ W,
    const float* __restrict__ U,
    float* __restrict__ out)
{
    // Position-centric restructure: for position p (token w) the 11 rows
    // U[w*11 + j], j=0..10 are ONE contiguous 5632 B slab; row j feeds output
    // l = p + 5 - j. Read whole slabs (contiguous 5.6 KB streams instead of
    // 11 scattered 512 B gathers) and max-reduce into an LDS output tile.
    __shared__ float tile[NR * EMB];   // 32 KB running max accumulator
    __shared__ float wt  [NR * EMB];   // 32 KB W rows of the 64 outputs
    __shared__ int   toks[NSLOTP];

    const int tid  = threadIdx.x;
    const int wv   = tid >> 6;         // wave 0..3
    const int lane = tid & 63;
    const int hw   = tid >> 5;         // half-wave 0..7
    const int hl   = tid & 31;         // lane within half-wave

    const int row0 = blockIdx.x * NR;  // global output row base
    const int b    = row0 >> 9;
    const int l0   = row0 & 511;
    const int* seqb = seq + (b << 9);

    // ---- stage the 74 window tokens (slot s <-> position p = l0 - 5 + s) ----
    if (tid < NSLOTP) {
        const int p = l0 - RR + tid;
        toks[tid] = (tid < NSLOT && p >= 0 && p < LL) ? seqb[p] : 0;
    }
    __syncthreads();

    f4* tile4 = (f4*)tile;
    f4* wt4   = (f4*)wt;

    // ---- stage W rows (coalesced 512 B per half-wave) + init tile ----
    #pragma unroll
    for (int rr = 0; rr < 8; ++rr) {
        const int r   = rr * 8 + hw;
        const int tok = toks[r + RR];            // this output row's own token
        wt4[r * 32 + hl] = ((const f4*)(W + (size_t)tok * EMB))[hl];
    }
    #pragma unroll
    for (int k = 0; k < 8; ++k)
        tile4[k * 256 + tid] = (f4){-INFINITY, -INFINITY, -INFINITY, -INFINITY};
    __syncthreads();

    // ---- main: each wave owns 20 slots, processed as 5 chunks of 4 ----
    // Chunk: load 4 slabs to registers (24 x 1 KB contiguous wave-loads),
    // then 11 sync'd j-phases. Race-free: within a phase, distinct slots ->
    // distinct output rows (r_out = slot - j); phases separated by barriers.
    const f4* U4 = (const f4*)U;
    const int s0w = wv * 20;

    for (int t = 0; t < 5; ++t) {
        const int s0 = s0w + t * 4;

        f4 u[4][6];                    // fully unrolled accesses -> registers
        #pragma unroll
        for (int c = 0; c < 4; ++c) {
            const int slot = s0 + c;   // wave-uniform guard
            if (slot < NSLOT) {
                const size_t base = (size_t)toks[slot] * (RS * 32); // f4 units
                #pragma unroll
                for (int k = 0; k < 5; ++k)
                    u[c][k] = U4[base + (size_t)(k * 64 + lane)];
                if (lane < 32)         // last half-slab; guard avoids OOB at U end
                    u[c][5] = U4[base + (size_t)(320 + lane)];
            }
        }

        #pragma unroll
        for (int j = 0; j < RS; ++j) {
            __syncthreads();
            const int k = j >> 1;      // register slot holding row j
            const int h = j & 1;       // which half-wave holds it
            #pragma unroll
            for (int c = 0; c < 4; ++c) {
                const int r_out = s0 + c - j;           // l = l0 + slot - j
                if (r_out >= 0 && r_out < NR && (lane >> 5) == h) {
                    const f4 uv = u[c][k];
                    const f4 tv = wt4[r_out * 32 + hl];
                    f4 cur = tile4[r_out * 32 + hl];
                    cur.x = fmaxf(cur.x, uv.x * tv.x);
                    cur.y = fmaxf(cur.y, uv.y * tv.y);
                    cur.z = fmaxf(cur.z, uv.z * tv.z);
                    cur.w = fmaxf(cur.w, uv.w * tv.w);
                    tile4[r_out * 32 + hl] = cur;
                }
            }
        }
    }

    // ---- epilogue: mask + NT store ----
    __syncthreads();
    #pragma unroll
    for (int rr = 0; rr < 8; ++rr) {
        const int r = rr * 8 + hw;
        const int s = toks[r + RR];
        f4 v = tile4[r * 32 + hl];
        if (s == 0) v = (f4){0.f, 0.f, 0.f, 0.f};
        __builtin_nontemporal_store(v, (f4*)(out + (size_t)(row0 + r) * EMB) + hl);
    }
}

extern "C" void kernel_launch(void* const* d_in, const int* in_sizes, int n_in,
                              void* d_out, int out_size, void* d_ws, size_t ws_size,
                              hipStream_t stream)
{
    const int*   seq = (const int*)  d_in[0];   // (B, L, 1) int32
    const float* W   = (const float*)d_in[1];   // (VOCAB, EMB) f32
    const float* U   = (const float*)d_in[2];   // (VOCAB*RS, EMB) f32
    float* out = (float*)d_out;                 // (B, L, 1, EMB) f32

    const int rows   = BB * LL;                 // 16384
    const int blocks = rows / NR;               // 256 blocks of 256 threads
    region_encoder_kernel<<<blocks, 256, 0, stream>>>(seq, W, U, out);
}

// Round 3
// 337.624 us; speedup vs baseline: 1.0676x; 1.0676x over previous
//
#include <hip/hip_runtime.h>

#define BB 32
#define LL 512
#define EMB 128
#define RS 11
#define RR 5

typedef float f4 __attribute__((ext_vector_type(4)));

__global__ __launch_bounds__(256) void region_encoder_kernel(
    const int* __restrict__ seq,
    const float* __restrict__ W,
    const float* __restrict__ U,
    float* __restrict__ out)
{
    // 32 lanes per output row; each lane owns one float4 (128 floats / row).
    // Best-measured structure (337.0 us total; kernel est. ~12 us, L3-resident
    // working set across graph replays). Round-2 slab restructure regressed
    // (+17-23 us: 55 barriers + half-idle lanes + LDS RMW) -> reverted.
    const int row  = blockIdx.x * 8 + (threadIdx.x >> 5);   // row in [0, B*L)
    const int lane = threadIdx.x & 31;

    const int b = row >> 9;       // row / 512
    const int l = row & 511;      // row % 512

    const int s = seq[row];

    const f4* W4 = (const f4*)(W + (size_t)s * EMB);
    const f4  t  = W4[lane];

    f4 m = (f4){-INFINITY, -INFINITY, -INFINITY, -INFINITY};

    #pragma unroll
    for (int j = 0; j < RS; ++j) {
        const int p = l + j - RR;
        const int w = (p >= 0 && p < LL) ? seq[(b << 9) + p] : 0;
        const f4* U4 = (const f4*)(U + (size_t)(w * RS + j) * EMB);
        const f4 u = __builtin_nontemporal_load(U4 + lane);
        m.x = fmaxf(m.x, u.x * t.x);
        m.y = fmaxf(m.y, u.y * t.y);
        m.z = fmaxf(m.z, u.z * t.z);
        m.w = fmaxf(m.w, u.w * t.w);
    }

    f4 r;
    if (s != 0) {
        r = m;
    } else {
        r = (f4){0.f, 0.f, 0.f, 0.f};
    }
    __builtin_nontemporal_store(r, (f4*)(out + (size_t)row * EMB) + lane);
}

extern "C" void kernel_launch(void* const* d_in, const int* in_sizes, int n_in,
                              void* d_out, int out_size, void* d_ws, size_t ws_size,
                              hipStream_t stream)
{
    const int*   seq = (const int*)  d_in[0];   // (B, L, 1) int32
    const float* W   = (const float*)d_in[1];   // (VOCAB, EMB) f32
    const float* U   = (const float*)d_in[2];   // (VOCAB*RS, EMB) f32
    float* out = (float*)d_out;                 // (B, L, 1, EMB) f32

    const int rows = BB * LL;                   // 16384
    const int blocks = rows / 8;                // 2048 blocks of 256 threads
    region_encoder_kernel<<<blocks, 256, 0, stream>>>(seq, W, U, out);
}